// Round 9
// baseline (905.760 us; speedup 1.0000x reference)
//
#include <hip/hip_runtime.h>
#include <stdint.h>

typedef unsigned short u16;
typedef __attribute__((ext_vector_type(8))) short s16x8;
typedef __attribute__((ext_vector_type(8))) unsigned short u16x8;
typedef __attribute__((ext_vector_type(4))) float f32x4;

#define N_TOK 8192
#define DDIM 2048
#define HDIM 2048
#define NROWS 16384
#define PADROWS 16640
#define MAXTILES 72
#define KTILES 32

// ---- ws layout (bytes) ----
#define W1T_OFF    0ull
#define W3T_OFF    67108864ull
#define W2T_OFF    134217728ull
#define XBF_OFF    201326592ull
#define HS_OFF     234881024ull              // 16640 x 2048 bf16
#define ROWTOK_OFF 303038464ull
#define POS_OFF    303107072ull
#define META_OFF   303172608ull
#define RES_OFF    0ull                      // overlays w1T/w3T (dead after gemm1)
#define WS_NEED    303172736ull

__device__ __forceinline__ u16 f2bf(float f) {
  union { float f; unsigned u; } v; v.f = f;
  unsigned r = v.u + 0x7fffu + ((v.u >> 16) & 1u);
  return (u16)(r >> 16);
}
__device__ __forceinline__ float bf2f(u16 u) {
  union { unsigned u; float f; } v; v.u = ((unsigned)u) << 16; return v.f;
}
__device__ __forceinline__ void gload_lds16(const u16* g, u16* l) {
  __builtin_amdgcn_global_load_lds(
      (const __attribute__((address_space(1))) unsigned int*)g,
      (__attribute__((address_space(3))) unsigned int*)l, 16, 0, 0);
}

// ---------------- routing ----------------
__global__ void r1_kernel(const int* __restrict__ bsz, int* __restrict__ meta,
                          int* __restrict__ rowtok) {
  if (threadIdx.x == 0) {
    int off = 0, tbv = 0;
    meta[8] = 0; meta[17] = 0;
    for (int e = 0; e < 8; ++e) {
      meta[e] = 0;
      int c = bsz[e];
      off += c;  meta[9 + e] = off;
      tbv += (c + 255) >> 8; meta[18 + e] = tbv;
    }
  }
  for (int p = NROWS + (int)threadIdx.x; p < PADROWS; p += 256) rowtok[p] = 0;
}

__global__ void r2_kernel(const int* __restrict__ eidx, int* __restrict__ meta,
                          int* __restrict__ rowtok, int* __restrict__ posOf) {
  int i = blockIdx.x * 256 + threadIdx.x;
  int e = eidx[i];
  int p = atomicAdd(&meta[e], 1);
  int row = meta[8 + e] + p;
  rowtok[row] = i >> 1;
  posOf[i] = row;
}

// ---------------- converts ----------------
__global__ void convert_x_kernel(const float* __restrict__ x, u16* __restrict__ xbf) {
  long long c = blockIdx.x * 256 + threadIdx.x;
  const float4 v0 = *(const float4*)&x[c * 8];
  const float4 v1 = *(const float4*)&x[c * 8 + 4];
  u16x8 u;
  u[0] = f2bf(v0.x); u[1] = f2bf(v0.y); u[2] = f2bf(v0.z); u[3] = f2bf(v0.w);
  u[4] = f2bf(v1.x); u[5] = f2bf(v1.y); u[6] = f2bf(v1.z); u[7] = f2bf(v1.w);
  *(u16x8*)&xbf[c * 8] = u;
}

__global__ __launch_bounds__(256) void transpose_cvt_kernel(
    const float* __restrict__ w1, const float* __restrict__ w2, const float* __restrict__ w3,
    u16* __restrict__ w1T, u16* __restrict__ w2T, u16* __restrict__ w3T) {
  __shared__ float tile[64][65];
  int z = blockIdx.z;
  const float* src; u16* dst;
  if (z < 8)        { src = w1 + (size_t)z * 4194304;        dst = w1T + (size_t)z * 4194304; }
  else if (z < 16)  { src = w3 + (size_t)(z - 8) * 4194304;  dst = w3T + (size_t)(z - 8) * 4194304; }
  else              { src = w2 + (size_t)(z - 16) * 4194304; dst = w2T + (size_t)(z - 16) * 4194304; }
  int r0 = blockIdx.y * 64, c0 = blockIdx.x * 64;
  int tid = threadIdx.x;
  int lr = tid >> 4, lc4 = (tid & 15) * 4;
#pragma unroll
  for (int i = 0; i < 4; ++i) {
    const float4 v = *(const float4*)&src[(size_t)(r0 + lr + i * 16) * 2048 + c0 + lc4];
    tile[lr + i * 16][lc4 + 0] = v.x; tile[lr + i * 16][lc4 + 1] = v.y;
    tile[lr + i * 16][lc4 + 2] = v.z; tile[lr + i * 16][lc4 + 3] = v.w;
  }
  __syncthreads();
  int orb = tid >> 3, oc8 = (tid & 7) * 8;
#pragma unroll
  for (int i = 0; i < 2; ++i) {
    int orow = orb + i * 32;
    u16x8 u;
#pragma unroll
    for (int j = 0; j < 8; ++j) u[j] = f2bf(tile[oc8 + j][orow]);
    *(u16x8*)&dst[(size_t)(c0 + orow) * 2048 + r0 + oc8] = u;
  }
}

// ---------------- grouped dual-B GEMM: A-direct-to-reg, B-only LDS ----------------
// Wave grid 4x2: wave = 64 rows x (64 cols per mat x 2 mats); acc1[4][4]+acc3[4][4].
// A fragments load global->VGPR (gathered rows; 16 rows x 64B per instr).
// LDS holds only B1,B3 (2 units x 16KB, double-buffered = 64 KiB).
// One __syncthreads per K-tile: drains vmcnt (certifies B stage + A regs) and
// orders buf reads (pre-barrier) vs next-tile overwrites (post-barrier).
template<int EPI>
__device__ __forceinline__ void gemm_body(
    const u16* __restrict__ A, const u16* __restrict__ B1m, const u16* __restrict__ B3m,
    const int* __restrict__ gather, const int* __restrict__ meta, u16* __restrict__ out) {
  const int* offs = meta + 8;
  const int* tb = meta + 17;

  // XCD super-block locality mapping (8 tileIds x 4 colbs per super-block)
  const int NCOLB = EPI ? 16 : 8;
  const int CG = NCOLB / 4;
  const int nper = (MAXTILES * NCOLB) / 8;
  const int lin = (int)blockIdx.x;
  const int w = (lin & 7) * nper + (lin >> 3);
  const int sb = w >> 5, t5 = w & 31;
  const int tileId = (sb / CG) * 8 + (t5 >> 2);
  const int colb = (sb % CG) * 4 + (t5 & 3);

  if (tileId >= tb[8]) return;
  int e = 0;
#pragma unroll
  for (int qq = 1; qq < 8; ++qq) if (tileId >= tb[qq]) e = qq;
  const int row0 = offs[e] + (tileId - tb[e]) * 256;
  const int vr = offs[e + 1] - row0;

  const int bRowA = EPI ? colb * 128 : colb * 256;
  const int bRowB = EPI ? colb * 128 : colb * 256 + 128;

  __shared__ u16 lds[2][2][8192];  // [buf][B1,B3] = 64 KiB

  const int tid = threadIdx.x;
  const int wid = tid >> 6, lane = tid & 63;
  const int lm = lane & 15, kg = lane >> 4;
  const int wr = wid >> 1, wc = wid & 1;   // 4x2 wave grid

  // ---- B stage pointers (2 loads per unit per thread), chunk-permuted source
  const u16* pB1[2]; const u16* pB3[2];
#pragma unroll
  for (int l = 0; l < 2; ++l) {
    int S = (wid * 2 + l) * 64 + lane;
    int r = S >> 3;
    int c8 = ((S & 7) ^ (r & 7)) * 8;
    pB1[l] = B1m + ((size_t)e * 2048 + bRowA + r) * 2048 + c8;
    pB3[l] = B3m + ((size_t)e * 2048 + bRowB + r) * 2048 + c8;
  }

  // ---- A direct-load pointers: per mi, lane reads row (wr*64+mi*16+lm), chunk kg
  const u16* pa[4];
#pragma unroll
  for (int mi = 0; mi < 4; ++mi) {
    int grow = row0 + wr * 64 + mi * 16 + lm;
    int ta = gather ? gather[grow] : grow;
    pa[mi] = A + (size_t)ta * 2048 + kg * 8;
  }

  // B frag-read offsets: elem = lm*64 + ((kk*4+kg)^(lm&7))*8
  int fA[2];
  fA[0] = lm * 64 + ((kg) ^ (lm & 7)) * 8;
  fA[1] = lm * 64 + ((4 + kg) ^ (lm & 7)) * 8;

  f32x4 acc1[4][4], acc3[4][4];
  f32x4 z4 = {0.f, 0.f, 0.f, 0.f};
#pragma unroll
  for (int m = 0; m < 4; ++m)
#pragma unroll
    for (int n = 0; n < 4; ++n) { acc1[m][n] = z4; acc3[m][n] = z4; }

  s16x8 aA[4][2], aB[4][2], b[2][2];

#define STG(bf, u, P) do { \
    gload_lds16(P[0], &lds[bf][u][(wid * 2 + 0) * 512]); \
    gload_lds16(P[1], &lds[bf][u][(wid * 2 + 1) * 512]); \
    P[0] += 64; P[1] += 64; } while (0)
#define LOAD_A(ar) do { \
_Pragma("unroll") \
    for (int mi = 0; mi < 4; ++mi) { \
      ar[mi][0] = *(const s16x8*)(pa[mi]); \
      ar[mi][1] = *(const s16x8*)(pa[mi] + 32); \
      pa[mi] += 64; } } while (0)
#define READ_B2(cur, unit, np) do { \
_Pragma("unroll") \
    for (int n = 0; n < 2; ++n) \
_Pragma("unroll") \
      for (int kk = 0; kk < 2; ++kk) \
        b[n][kk] = *(const s16x8*)&lds[cur][unit][wc * 4096 + ((np) * 2 + n) * 1024 + fA[kk]]; \
    } while (0)
#define MFMA16G(ACC, np, ar) do { \
    __builtin_amdgcn_s_setprio(1); \
_Pragma("unroll") \
    for (int mi = 0; mi < 4; ++mi) \
_Pragma("unroll") \
      for (int n = 0; n < 2; ++n) { \
        ACC[mi][(np) * 2 + n] = __builtin_amdgcn_mfma_f32_16x16x32_bf16(ar[mi][0], b[n][0], ACC[mi][(np) * 2 + n], 0, 0, 0); \
        ACC[mi][(np) * 2 + n] = __builtin_amdgcn_mfma_f32_16x16x32_bf16(ar[mi][1], b[n][1], ACC[mi][(np) * 2 + n], 0, 0, 0); \
      } \
    __builtin_amdgcn_s_setprio(0); } while (0)

  // TILE: computes K-tile t from buf[cur]/aC; stages B(t+1) into buf^1 and
  // loads A(t+1) into aN (when STAGE). __syncthreads certifies everything.
#define TILE(cur, aC, aN, STAGE) do { \
    if (STAGE) { STG(cur ^ 1, 0, pB1); STG(cur ^ 1, 1, pB3); LOAD_A(aN); } \
    READ_B2(cur, 0, 0); MFMA16G(acc1, 0, aC); \
    READ_B2(cur, 0, 1); MFMA16G(acc1, 1, aC); \
    READ_B2(cur, 1, 0); MFMA16G(acc3, 0, aC); \
    READ_B2(cur, 1, 1); MFMA16G(acc3, 1, aC); \
    __syncthreads(); } while (0)

  // prologue: stage tile 0 (B->LDS, A->aA), full drain
  STG(0, 0, pB1);
  STG(0, 1, pB3);
  LOAD_A(aA);
  __syncthreads();

  for (int t = 0; t < KTILES - 2; t += 2) {
    TILE(0, aA, aB, 1);
    TILE(1, aB, aA, 1);
  }
  TILE(0, aA, aB, 1);
  TILE(1, aB, aA, 0);

  // ---- epilogue
#pragma unroll
  for (int m = 0; m < 4; ++m)
#pragma unroll
    for (int n = 0; n < 4; ++n) {
      const int rloc = wr * 64 + m * 16 + kg * 4;
      if (EPI == 1) {
        const int col = colb * 128 + wc * 64 + n * 16 + lm;
#pragma unroll
        for (int rr = 0; rr < 4; ++rr) {
          int rowl = rloc + rr;
          if (rowl < vr) {
            float z = acc1[m][n][rr];
            float h = z / (1.f + __expf(-z)) * acc3[m][n][rr];
            out[(size_t)(row0 + rowl) * 2048 + col] = f2bf(h);
          }
        }
      } else {
        const int col = colb * 256 + wc * 64 + n * 16 + lm;
#pragma unroll
        for (int rr = 0; rr < 4; ++rr) {
          int rowl = rloc + rr;
          if (rowl < vr) {
            out[(size_t)(row0 + rowl) * 2048 + col] = f2bf(acc1[m][n][rr]);
            out[(size_t)(row0 + rowl) * 2048 + col + 128] = f2bf(acc3[m][n][rr]);
          }
        }
      }
    }
#undef STG
#undef LOAD_A
#undef READ_B2
#undef MFMA16G
#undef TILE
}

__global__ __launch_bounds__(512, 2) void gemm1_kernel(
    const u16* __restrict__ A, const u16* __restrict__ B1m, const u16* __restrict__ B3m,
    const int* __restrict__ gather, const int* __restrict__ meta, u16* __restrict__ out) {
  gemm_body<1>(A, B1m, B3m, gather, meta, out);
}
__global__ __launch_bounds__(512, 2) void gemm2_kernel(
    const u16* __restrict__ A, const u16* __restrict__ B1m, const u16* __restrict__ B3m,
    const int* __restrict__ gather, const int* __restrict__ meta, u16* __restrict__ out) {
  gemm_body<0>(A, B1m, B3m, gather, meta, out);
}

// ---------------- combine ----------------
__global__ void combine_kernel(const u16* __restrict__ res, const int* __restrict__ posOf,
                               const float* __restrict__ ew, float* __restrict__ out) {
  int c = blockIdx.x * 256 + threadIdx.x;
  int t = c >> 8, dc = (c & 255) * 8;
  int p0 = posOf[2 * t], p1 = posOf[2 * t + 1];
  float wa = ew[2 * t], wb = ew[2 * t + 1];
  u16x8 u0 = *(const u16x8*)&res[(size_t)p0 * 2048 + dc];
  u16x8 u1 = *(const u16x8*)&res[(size_t)p1 * 2048 + dc];
  float4 o0, o1;
  o0.x = wa * bf2f(u0[0]) + wb * bf2f(u1[0]);
  o0.y = wa * bf2f(u0[1]) + wb * bf2f(u1[1]);
  o0.z = wa * bf2f(u0[2]) + wb * bf2f(u1[2]);
  o0.w = wa * bf2f(u0[3]) + wb * bf2f(u1[3]);
  o1.x = wa * bf2f(u0[4]) + wb * bf2f(u1[4]);
  o1.y = wa * bf2f(u0[5]) + wb * bf2f(u1[5]);
  o1.z = wa * bf2f(u0[6]) + wb * bf2f(u1[6]);
  o1.w = wa * bf2f(u0[7]) + wb * bf2f(u1[7]);
  *(float4*)&out[(size_t)t * 2048 + dc] = o0;
  *(float4*)&out[(size_t)t * 2048 + dc + 4] = o1;
}

extern "C" void kernel_launch(void* const* d_in, const int* in_sizes, int n_in,
                              void* d_out, int out_size, void* d_ws, size_t ws_size,
                              hipStream_t stream) {
  const float* x  = (const float*)d_in[0];
  const float* ew = (const float*)d_in[1];
  const int* eidx = (const int*)d_in[2];
  const int* bsz  = (const int*)d_in[3];
  const float* w1 = (const float*)d_in[4];
  const float* w2 = (const float*)d_in[5];
  const float* w3 = (const float*)d_in[6];
  float* out = (float*)d_out;
  char* ws = (char*)d_ws;

  if (ws_size < WS_NEED) {
    hipMemsetAsync(d_out, 0, (size_t)out_size * 4, stream);
    return;
  }

  u16* w1T = (u16*)(ws + W1T_OFF);
  u16* w3T = (u16*)(ws + W3T_OFF);
  u16* w2T = (u16*)(ws + W2T_OFF);
  u16* xbf = (u16*)(ws + XBF_OFF);
  u16* hs  = (u16*)(ws + HS_OFF);
  u16* res = (u16*)(ws + RES_OFF);   // overlays w1T/w3T (dead after gemm1)
  int* rowtok = (int*)(ws + ROWTOK_OFF);
  int* posOf  = (int*)(ws + POS_OFF);
  int* meta   = (int*)(ws + META_OFF);

  r1_kernel<<<1, 256, 0, stream>>>(bsz, meta, rowtok);
  r2_kernel<<<64, 256, 0, stream>>>(eidx, meta, rowtok, posOf);
  convert_x_kernel<<<8192, 256, 0, stream>>>(x, xbf);
  transpose_cvt_kernel<<<dim3(32, 32, 24), 256, 0, stream>>>(w1, w2, w3, w1T, w2T, w3T);
  gemm1_kernel<<<MAXTILES * 16, 512, 0, stream>>>(xbf, w1T, w3T, rowtok, meta, hs);
  gemm2_kernel<<<MAXTILES * 8, 512, 0, stream>>>(hs, w2T, w2T, nullptr, meta, res);
  combine_kernel<<<8192, 256, 0, stream>>>(res, posOf, ew, out);
}

// Round 10
// 748.871 us; speedup vs baseline: 1.2095x; 1.2095x over previous
//
#include <hip/hip_runtime.h>
#include <stdint.h>

typedef unsigned short u16;
typedef __attribute__((ext_vector_type(8))) short s16x8;
typedef __attribute__((ext_vector_type(8))) unsigned short u16x8;
typedef __attribute__((ext_vector_type(4))) float f32x4;

#define N_TOK 8192
#define DDIM 2048
#define HDIM 2048
#define NROWS 16384
#define PADROWS 17408
#define MAXTILES 136
#define KTILES 64

// ---- ws layout (bytes) ----
#define W1T_OFF    0ull
#define W3T_OFF    67108864ull
#define W2T_OFF    134217728ull
#define XBF_OFF    201326592ull
#define HS_OFF     234881024ull              // 16640 x 2048 bf16
#define ROWTOK_OFF 303038464ull              // 17408 ints
#define POS_OFF    303108096ull              // 16384 ints
#define META_OFF   303173632ull
#define RES_OFF    0ull                      // overlays w1T/w3T (dead after gemm1)
#define WS_NEED    303173760ull

__device__ __forceinline__ u16 f2bf(float f) {
  union { float f; unsigned u; } v; v.f = f;
  unsigned r = v.u + 0x7fffu + ((v.u >> 16) & 1u);
  return (u16)(r >> 16);
}
__device__ __forceinline__ float bf2f(u16 u) {
  union { unsigned u; float f; } v; v.u = ((unsigned)u) << 16; return v.f;
}
__device__ __forceinline__ void gload_lds16(const u16* g, u16* l) {
  __builtin_amdgcn_global_load_lds(
      (const __attribute__((address_space(1))) unsigned int*)g,
      (__attribute__((address_space(3))) unsigned int*)l, 16, 0, 0);
}

// ---------------- routing (128-row tiles) ----------------
__global__ void r1_kernel(const int* __restrict__ bsz, int* __restrict__ meta,
                          int* __restrict__ rowtok) {
  if (threadIdx.x == 0) {
    int off = 0, tbv = 0;
    meta[8] = 0; meta[17] = 0;
    for (int e = 0; e < 8; ++e) {
      meta[e] = 0;
      int c = bsz[e];
      off += c;  meta[9 + e] = off;
      tbv += (c + 127) >> 7; meta[18 + e] = tbv;   // 128-row tiles
    }
  }
  for (int p = NROWS + (int)threadIdx.x; p < PADROWS; p += 256) rowtok[p] = 0;
}

__global__ void r2_kernel(const int* __restrict__ eidx, int* __restrict__ meta,
                          int* __restrict__ rowtok, int* __restrict__ posOf) {
  int i = blockIdx.x * 256 + threadIdx.x;
  int e = eidx[i];
  int p = atomicAdd(&meta[e], 1);
  int row = meta[8 + e] + p;
  rowtok[row] = i >> 1;
  posOf[i] = row;
}

// ---------------- converts ----------------
__global__ void convert_x_kernel(const float* __restrict__ x, u16* __restrict__ xbf) {
  long long c = blockIdx.x * 256 + threadIdx.x;
  const float4 v0 = *(const float4*)&x[c * 8];
  const float4 v1 = *(const float4*)&x[c * 8 + 4];
  u16x8 u;
  u[0] = f2bf(v0.x); u[1] = f2bf(v0.y); u[2] = f2bf(v0.z); u[3] = f2bf(v0.w);
  u[4] = f2bf(v1.x); u[5] = f2bf(v1.y); u[6] = f2bf(v1.z); u[7] = f2bf(v1.w);
  *(u16x8*)&xbf[c * 8] = u;
}

__global__ __launch_bounds__(256) void transpose_cvt_kernel(
    const float* __restrict__ w1, const float* __restrict__ w2, const float* __restrict__ w3,
    u16* __restrict__ w1T, u16* __restrict__ w2T, u16* __restrict__ w3T) {
  __shared__ float tile[64][65];
  int z = blockIdx.z;
  const float* src; u16* dst;
  if (z < 8)        { src = w1 + (size_t)z * 4194304;        dst = w1T + (size_t)z * 4194304; }
  else if (z < 16)  { src = w3 + (size_t)(z - 8) * 4194304;  dst = w3T + (size_t)(z - 8) * 4194304; }
  else              { src = w2 + (size_t)(z - 16) * 4194304; dst = w2T + (size_t)(z - 16) * 4194304; }
  int r0 = blockIdx.y * 64, c0 = blockIdx.x * 64;
  int tid = threadIdx.x;
  int lr = tid >> 4, lc4 = (tid & 15) * 4;
#pragma unroll
  for (int i = 0; i < 4; ++i) {
    const float4 v = *(const float4*)&src[(size_t)(r0 + lr + i * 16) * 2048 + c0 + lc4];
    tile[lr + i * 16][lc4 + 0] = v.x; tile[lr + i * 16][lc4 + 1] = v.y;
    tile[lr + i * 16][lc4 + 2] = v.z; tile[lr + i * 16][lc4 + 3] = v.w;
  }
  __syncthreads();
  int orb = tid >> 3, oc8 = (tid & 7) * 8;
#pragma unroll
  for (int i = 0; i < 2; ++i) {
    int orow = orb + i * 32;
    u16x8 u;
#pragma unroll
    for (int j = 0; j < 8; ++j) u[j] = f2bf(tile[oc8 + j][orow]);
    *(u16x8*)&dst[(size_t)(c0 + orow) * 2048 + r0 + oc8] = u;
  }
}

// ---------------- grouped dual-B GEMM, m97-class resourcing ----------------
// 256 threads / 4 waves (2x2), tile 128 rows x 64 cols per mat, BK=32, LDS 32KB
// -> ~3 blocks/CU so barrier/waitcnt stalls overlap across blocks (m114).
// Schedule per K-tile (proven R8 pattern): STG(t+1); vmcnt(4); BAR; ds_reads;
// BAR; MFMA. vmcnt counted (never drains in main loop).
// EPI=1: out[row][colb*64+c]  = silu(A@B1) * (A@B3)
// EPI=0: out[row][colb*128+c] = A@B1 ; +64 = A@B3 (both = w2T sub-panels)
template<int EPI>
__device__ __forceinline__ void gemm_body(
    const u16* __restrict__ A, const u16* __restrict__ B1m, const u16* __restrict__ B3m,
    const int* __restrict__ gather, const int* __restrict__ meta, u16* __restrict__ out) {
  const int* offs = meta + 8;
  const int* tb = meta + 17;

  // XCD super-block walk: 8 tileIds x 4 colbs per super-block
  const int NCOLB = EPI ? 32 : 16;
  const int CG = NCOLB / 4;
  const int nper = (MAXTILES * NCOLB) / 8;
  const int lin = (int)blockIdx.x;
  const int w = (lin & 7) * nper + (lin >> 3);
  const int sb = w >> 5, t5 = w & 31;
  const int tileId = (sb / CG) * 8 + (t5 >> 2);
  const int colb = (sb % CG) * 4 + (t5 & 3);

  if (tileId >= tb[8]) return;
  int e = 0;
#pragma unroll
  for (int qq = 1; qq < 8; ++qq) if (tileId >= tb[qq]) e = qq;
  const int row0 = offs[e] + (tileId - tb[e]) * 128;
  const int vr = offs[e + 1] - row0;

  const int bRowA = EPI ? colb * 64 : colb * 128;
  const int bRowB = EPI ? colb * 64 : colb * 128 + 64;

  // flat per-buf layout (u16): A @0 (128x32=4096), B1 @4096 (64x32), B3 @6144
  __shared__ u16 lds[2][8192];   // 32 KiB

  const int tid = threadIdx.x;
  const int wid = tid >> 6, lane = tid & 63;
  const int lm = lane & 15, kg = lane >> 4;
  const int wr = wid >> 1, wc = wid & 1;   // 2x2 wave grid

  // ---- stage pointers; source chunk-permuted to match swizzled read
  // slot s holds row r=s>>2, chunk c=(s&3)^((r>>1)&3) (16B chunks, 4/row)
  const u16* pA[2]; const u16* pB1; const u16* pB3;
  int dA[2], dB1, dB3;
#pragma unroll
  for (int l = 0; l < 2; ++l) {
    int S = (wid + l * 4) * 64 + lane;      // 0..511
    int r = S >> 2;
    int c8 = ((S & 3) ^ ((r >> 1) & 3)) * 8;
    int ga = row0 + r;
    int ta = gather ? gather[ga] : ga;
    pA[l] = A + (size_t)ta * 2048 + c8;
    dA[l] = (wid + l * 4) * 512;
  }
  {
    int S = wid * 64 + lane;                // 0..255
    int r = S >> 2;
    int c8 = ((S & 3) ^ ((r >> 1) & 3)) * 8;
    pB1 = B1m + ((size_t)e * 2048 + bRowA + r) * 2048 + c8;
    pB3 = B3m + ((size_t)e * 2048 + bRowB + r) * 2048 + c8;
    dB1 = 4096 + wid * 512;
    dB3 = 6144 + wid * 512;
  }

  // read offsets: row base + lm rows; k-chunk kg swizzled by ((row>>1)&3)=(lm>>1)&3
  const int fK = (kg ^ ((lm >> 1) & 3)) * 8;
  const int aBase  = (wr * 64 + lm) * 32 + fK;
  const int b1Base = 4096 + (wc * 32 + lm) * 32 + fK;

  f32x4 acc1[4][2], acc3[4][2];
  f32x4 z4 = {0.f, 0.f, 0.f, 0.f};
#pragma unroll
  for (int m = 0; m < 4; ++m)
#pragma unroll
    for (int n = 0; n < 2; ++n) { acc1[m][n] = z4; acc3[m][n] = z4; }

  s16x8 a[4], b1[2], b3[2];

#define STG_ALL(bf) do { \
    gload_lds16(pA[0], &lds[bf][dA[0]]); \
    gload_lds16(pA[1], &lds[bf][dA[1]]); \
    gload_lds16(pB1,   &lds[bf][dB1]); \
    gload_lds16(pB3,   &lds[bf][dB3]); \
    pA[0] += 32; pA[1] += 32; pB1 += 32; pB3 += 32; } while (0)
#define READS(cur) do { \
_Pragma("unroll") \
    for (int mi = 0; mi < 4; ++mi) \
      a[mi] = *(const s16x8*)&lds[cur][aBase + mi * 512]; \
_Pragma("unroll") \
    for (int n = 0; n < 2; ++n) { \
      b1[n] = *(const s16x8*)&lds[cur][b1Base + n * 512]; \
      b3[n] = *(const s16x8*)&lds[cur][b1Base + 2048 + n * 512]; \
    } } while (0)
#define MFMA16() do { \
    __builtin_amdgcn_s_setprio(1); \
_Pragma("unroll") \
    for (int mi = 0; mi < 4; ++mi) \
_Pragma("unroll") \
      for (int n = 0; n < 2; ++n) { \
        acc1[mi][n] = __builtin_amdgcn_mfma_f32_16x16x32_bf16(a[mi], b1[n], acc1[mi][n], 0, 0, 0); \
        acc3[mi][n] = __builtin_amdgcn_mfma_f32_16x16x32_bf16(a[mi], b3[n], acc3[mi][n], 0, 0, 0); \
      } \
    __builtin_amdgcn_s_setprio(0); } while (0)

#define TILE_MAIN(cur) do { \
    STG_ALL(cur ^ 1); \
    asm volatile("s_waitcnt vmcnt(4)" ::: "memory"); \
    __builtin_amdgcn_s_barrier(); \
    READS(cur); \
    __builtin_amdgcn_s_barrier(); \
    MFMA16(); } while (0)
#define TILE_LAST(cur) do { \
    asm volatile("s_waitcnt vmcnt(0)" ::: "memory"); \
    __builtin_amdgcn_s_barrier(); \
    READS(cur); \
    MFMA16(); } while (0)

  // prologue: stage tile 0 (4 loads in flight)
  STG_ALL(0);

  for (int t = 0; t < KTILES - 2; t += 2) {
    TILE_MAIN(0);
    TILE_MAIN(1);
  }
  TILE_MAIN(0);
  TILE_LAST(1);

  // ---- epilogue
#pragma unroll
  for (int m = 0; m < 4; ++m)
#pragma unroll
    for (int n = 0; n < 2; ++n) {
      const int rloc = wr * 64 + m * 16 + kg * 4;
      if (EPI == 1) {
        const int col = colb * 64 + wc * 32 + n * 16 + lm;
#pragma unroll
        for (int rr = 0; rr < 4; ++rr) {
          int rowl = rloc + rr;
          if (rowl < vr) {
            float z = acc1[m][n][rr];
            float h = z / (1.f + __expf(-z)) * acc3[m][n][rr];
            out[(size_t)(row0 + rowl) * 2048 + col] = f2bf(h);
          }
        }
      } else {
        const int col = colb * 128 + wc * 32 + n * 16 + lm;
#pragma unroll
        for (int rr = 0; rr < 4; ++rr) {
          int rowl = rloc + rr;
          if (rowl < vr) {
            out[(size_t)(row0 + rowl) * 2048 + col] = f2bf(acc1[m][n][rr]);
            out[(size_t)(row0 + rowl) * 2048 + col + 64] = f2bf(acc3[m][n][rr]);
          }
        }
      }
    }
#undef STG_ALL
#undef READS
#undef MFMA16
#undef TILE_MAIN
#undef TILE_LAST
}

__global__ __launch_bounds__(256, 3) void gemm1_kernel(
    const u16* __restrict__ A, const u16* __restrict__ B1m, const u16* __restrict__ B3m,
    const int* __restrict__ gather, const int* __restrict__ meta, u16* __restrict__ out) {
  gemm_body<1>(A, B1m, B3m, gather, meta, out);
}
__global__ __launch_bounds__(256, 3) void gemm2_kernel(
    const u16* __restrict__ A, const u16* __restrict__ B1m, const u16* __restrict__ B3m,
    const int* __restrict__ gather, const int* __restrict__ meta, u16* __restrict__ out) {
  gemm_body<0>(A, B1m, B3m, gather, meta, out);
}

// ---------------- combine ----------------
__global__ void combine_kernel(const u16* __restrict__ res, const int* __restrict__ posOf,
                               const float* __restrict__ ew, float* __restrict__ out) {
  int c = blockIdx.x * 256 + threadIdx.x;
  int t = c >> 8, dc = (c & 255) * 8;
  int p0 = posOf[2 * t], p1 = posOf[2 * t + 1];
  float wa = ew[2 * t], wb = ew[2 * t + 1];
  u16x8 u0 = *(const u16x8*)&res[(size_t)p0 * 2048 + dc];
  u16x8 u1 = *(const u16x8*)&res[(size_t)p1 * 2048 + dc];
  float4 o0, o1;
  o0.x = wa * bf2f(u0[0]) + wb * bf2f(u1[0]);
  o0.y = wa * bf2f(u0[1]) + wb * bf2f(u1[1]);
  o0.z = wa * bf2f(u0[2]) + wb * bf2f(u1[2]);
  o0.w = wa * bf2f(u0[3]) + wb * bf2f(u1[3]);
  o1.x = wa * bf2f(u0[4]) + wb * bf2f(u1[4]);
  o1.y = wa * bf2f(u0[5]) + wb * bf2f(u1[5]);
  o1.z = wa * bf2f(u0[6]) + wb * bf2f(u1[6]);
  o1.w = wa * bf2f(u0[7]) + wb * bf2f(u1[7]);
  *(float4*)&out[(size_t)t * 2048 + dc] = o0;
  *(float4*)&out[(size_t)t * 2048 + dc + 4] = o1;
}

extern "C" void kernel_launch(void* const* d_in, const int* in_sizes, int n_in,
                              void* d_out, int out_size, void* d_ws, size_t ws_size,
                              hipStream_t stream) {
  const float* x  = (const float*)d_in[0];
  const float* ew = (const float*)d_in[1];
  const int* eidx = (const int*)d_in[2];
  const int* bsz  = (const int*)d_in[3];
  const float* w1 = (const float*)d_in[4];
  const float* w2 = (const float*)d_in[5];
  const float* w3 = (const float*)d_in[6];
  float* out = (float*)d_out;
  char* ws = (char*)d_ws;

  if (ws_size < WS_NEED) {
    hipMemsetAsync(d_out, 0, (size_t)out_size * 4, stream);
    return;
  }

  u16* w1T = (u16*)(ws + W1T_OFF);
  u16* w3T = (u16*)(ws + W3T_OFF);
  u16* w2T = (u16*)(ws + W2T_OFF);
  u16* xbf = (u16*)(ws + XBF_OFF);
  u16* hs  = (u16*)(ws + HS_OFF);
  u16* res = (u16*)(ws + RES_OFF);   // overlays w1T/w3T (dead after gemm1)
  int* rowtok = (int*)(ws + ROWTOK_OFF);
  int* posOf  = (int*)(ws + POS_OFF);
  int* meta   = (int*)(ws + META_OFF);

  r1_kernel<<<1, 256, 0, stream>>>(bsz, meta, rowtok);
  r2_kernel<<<64, 256, 0, stream>>>(eidx, meta, rowtok, posOf);
  convert_x_kernel<<<8192, 256, 0, stream>>>(x, xbf);
  transpose_cvt_kernel<<<dim3(32, 32, 24), 256, 0, stream>>>(w1, w2, w3, w1T, w2T, w3T);
  gemm1_kernel<<<MAXTILES * 32, 256, 0, stream>>>(xbf, w1T, w3T, rowtok, meta, hs);
  gemm2_kernel<<<MAXTILES * 16, 256, 0, stream>>>(hs, w2T, w2T, nullptr, meta, res);
  combine_kernel<<<8192, 256, 0, stream>>>(res, posOf, ew, out);
}

// Round 11
// 736.525 us; speedup vs baseline: 1.2298x; 1.0168x over previous
//
#include <hip/hip_runtime.h>
#include <stdint.h>

typedef unsigned short u16;
typedef __attribute__((ext_vector_type(8))) short s16x8;
typedef __attribute__((ext_vector_type(8))) unsigned short u16x8;
typedef __attribute__((ext_vector_type(4))) float f32x4;

#define N_TOK 8192
#define DDIM 2048
#define HDIM 2048
#define NROWS 16384
#define PADROWS 17408
#define MAXTILES 136
#define KTILES 64

// ---- ws layout (bytes) ----
#define W1T_OFF    0ull
#define W3T_OFF    67108864ull
#define W2T_OFF    134217728ull
#define XBF_OFF    201326592ull
#define HS_OFF     234881024ull              // 16640 x 2048 bf16
#define ROWTOK_OFF 303038464ull              // 17408 ints
#define POS_OFF    303108096ull              // 16384 ints
#define META_OFF   303173632ull
#define RES_OFF    0ull                      // overlays w1T/w3T (dead after gemm1)
#define WS_NEED    303173760ull

__device__ __forceinline__ u16 f2bf(float f) {
  union { float f; unsigned u; } v; v.f = f;
  unsigned r = v.u + 0x7fffu + ((v.u >> 16) & 1u);
  return (u16)(r >> 16);
}
__device__ __forceinline__ float bf2f(u16 u) {
  union { unsigned u; float f; } v; v.u = ((unsigned)u) << 16; return v.f;
}
__device__ __forceinline__ void gload_lds16(const u16* g, u16* l) {
  __builtin_amdgcn_global_load_lds(
      (const __attribute__((address_space(1))) unsigned int*)g,
      (__attribute__((address_space(3))) unsigned int*)l, 16, 0, 0);
}

// ---------------- routing (128-row tiles) ----------------
__global__ void r1_kernel(const int* __restrict__ bsz, int* __restrict__ meta,
                          int* __restrict__ rowtok) {
  if (threadIdx.x == 0) {
    int off = 0, tbv = 0;
    meta[8] = 0; meta[17] = 0;
    for (int e = 0; e < 8; ++e) {
      meta[e] = 0;
      int c = bsz[e];
      off += c;  meta[9 + e] = off;
      tbv += (c + 127) >> 7; meta[18 + e] = tbv;   // 128-row tiles
    }
  }
  for (int p = NROWS + (int)threadIdx.x; p < PADROWS; p += 256) rowtok[p] = 0;
}

__global__ void r2_kernel(const int* __restrict__ eidx, int* __restrict__ meta,
                          int* __restrict__ rowtok, int* __restrict__ posOf) {
  int i = blockIdx.x * 256 + threadIdx.x;
  int e = eidx[i];
  int p = atomicAdd(&meta[e], 1);
  int row = meta[8 + e] + p;
  rowtok[row] = i >> 1;
  posOf[i] = row;
}

// ---------------- converts ----------------
__global__ void convert_x_kernel(const float* __restrict__ x, u16* __restrict__ xbf) {
  long long c = blockIdx.x * 256 + threadIdx.x;
  const float4 v0 = *(const float4*)&x[c * 8];
  const float4 v1 = *(const float4*)&x[c * 8 + 4];
  u16x8 u;
  u[0] = f2bf(v0.x); u[1] = f2bf(v0.y); u[2] = f2bf(v0.z); u[3] = f2bf(v0.w);
  u[4] = f2bf(v1.x); u[5] = f2bf(v1.y); u[6] = f2bf(v1.z); u[7] = f2bf(v1.w);
  *(u16x8*)&xbf[c * 8] = u;
}

__global__ __launch_bounds__(256) void transpose_cvt_kernel(
    const float* __restrict__ w1, const float* __restrict__ w2, const float* __restrict__ w3,
    u16* __restrict__ w1T, u16* __restrict__ w2T, u16* __restrict__ w3T) {
  __shared__ float tile[64][65];
  int z = blockIdx.z;
  const float* src; u16* dst;
  if (z < 8)        { src = w1 + (size_t)z * 4194304;        dst = w1T + (size_t)z * 4194304; }
  else if (z < 16)  { src = w3 + (size_t)(z - 8) * 4194304;  dst = w3T + (size_t)(z - 8) * 4194304; }
  else              { src = w2 + (size_t)(z - 16) * 4194304; dst = w2T + (size_t)(z - 16) * 4194304; }
  int r0 = blockIdx.y * 64, c0 = blockIdx.x * 64;
  int tid = threadIdx.x;
  int lr = tid >> 4, lc4 = (tid & 15) * 4;
#pragma unroll
  for (int i = 0; i < 4; ++i) {
    const float4 v = *(const float4*)&src[(size_t)(r0 + lr + i * 16) * 2048 + c0 + lc4];
    tile[lr + i * 16][lc4 + 0] = v.x; tile[lr + i * 16][lc4 + 1] = v.y;
    tile[lr + i * 16][lc4 + 2] = v.z; tile[lr + i * 16][lc4 + 3] = v.w;
  }
  __syncthreads();
  int orb = tid >> 3, oc8 = (tid & 7) * 8;
#pragma unroll
  for (int i = 0; i < 2; ++i) {
    int orow = orb + i * 32;
    u16x8 u;
#pragma unroll
    for (int j = 0; j < 8; ++j) u[j] = f2bf(tile[oc8 + j][orow]);
    *(u16x8*)&dst[(size_t)(c0 + orow) * 2048 + r0 + oc8] = u;
  }
}

// ---------------- grouped dual-B GEMM, ring-4 deep prefetch ----------------
// 256 threads / 4 waves (2x2), tile 128 rows x 64 cols per mat, BK=32.
// LDS ring of 4 buffers (64 KiB): tile t stages t+3 -> issue-to-wait distance
// = 3 tiles (~1000 cyc) > HBM latency (~900), so counted vmcnt(12) never
// exposes memory latency. 2 barriers/tile (proven R8/R10 pattern).
// EPI=1: out[row][colb*64+c]  = silu(A@B1) * (A@B3)
// EPI=0: out[row][colb*128+c] = A@B1 ; +64 = A@B3 (both = w2T sub-panels)
template<int EPI>
__device__ __forceinline__ void gemm_body(
    const u16* __restrict__ A, const u16* __restrict__ B1m, const u16* __restrict__ B3m,
    const int* __restrict__ gather, const int* __restrict__ meta, u16* __restrict__ out) {
  const int* offs = meta + 8;
  const int* tb = meta + 17;

  // XCD super-block walk: 8 tileIds x 4 colbs per super-block
  const int NCOLB = EPI ? 32 : 16;
  const int CG = NCOLB / 4;
  const int nper = (MAXTILES * NCOLB) / 8;
  const int lin = (int)blockIdx.x;
  const int w = (lin & 7) * nper + (lin >> 3);
  const int sb = w >> 5, t5 = w & 31;
  const int tileId = (sb / CG) * 8 + (t5 >> 2);
  const int colb = (sb % CG) * 4 + (t5 & 3);

  if (tileId >= tb[8]) return;
  int e = 0;
#pragma unroll
  for (int qq = 1; qq < 8; ++qq) if (tileId >= tb[qq]) e = qq;
  const int row0 = offs[e] + (tileId - tb[e]) * 128;
  const int vr = offs[e + 1] - row0;

  const int bRowA = EPI ? colb * 64 : colb * 128;
  const int bRowB = EPI ? colb * 64 : colb * 128 + 64;

  // flat per-buf layout (u16): A @0 (128x32=4096), B1 @4096 (64x32), B3 @6144
  __shared__ u16 lds[4][8192];   // 64 KiB ring

  const int tid = threadIdx.x;
  const int wid = tid >> 6, lane = tid & 63;
  const int lm = lane & 15, kg = lane >> 4;
  const int wr = wid >> 1, wc = wid & 1;   // 2x2 wave grid

  // ---- stage pointers; source chunk-permuted to match swizzled read
  // slot s holds row r=s>>2, chunk c=(s&3)^((r>>1)&3) (16B chunks, 4/row)
  const u16* pA[2]; const u16* pB1; const u16* pB3;
  int dA[2], dB1, dB3;
#pragma unroll
  for (int l = 0; l < 2; ++l) {
    int S = (wid + l * 4) * 64 + lane;      // 0..511
    int r = S >> 2;
    int c8 = ((S & 3) ^ ((r >> 1) & 3)) * 8;
    int ga = row0 + r;
    int ta = gather ? gather[ga] : ga;
    pA[l] = A + (size_t)ta * 2048 + c8;
    dA[l] = (wid + l * 4) * 512;
  }
  {
    int S = wid * 64 + lane;                // 0..255
    int r = S >> 2;
    int c8 = ((S & 3) ^ ((r >> 1) & 3)) * 8;
    pB1 = B1m + ((size_t)e * 2048 + bRowA + r) * 2048 + c8;
    pB3 = B3m + ((size_t)e * 2048 + bRowB + r) * 2048 + c8;
    dB1 = 4096 + wid * 512;
    dB3 = 6144 + wid * 512;
  }

  // read offsets: row base + lm rows; k-chunk kg swizzled by ((row>>1)&3)=(lm>>1)&3
  const int fK = (kg ^ ((lm >> 1) & 3)) * 8;
  const int aBase  = (wr * 64 + lm) * 32 + fK;
  const int b1Base = 4096 + (wc * 32 + lm) * 32 + fK;

  f32x4 acc1[4][2], acc3[4][2];
  f32x4 z4 = {0.f, 0.f, 0.f, 0.f};
#pragma unroll
  for (int m = 0; m < 4; ++m)
#pragma unroll
    for (int n = 0; n < 2; ++n) { acc1[m][n] = z4; acc3[m][n] = z4; }

  s16x8 a[4], b1[2], b3[2];

#define STG_ALL(bf) do { \
    gload_lds16(pA[0], &lds[bf][dA[0]]); \
    gload_lds16(pA[1], &lds[bf][dA[1]]); \
    gload_lds16(pB1,   &lds[bf][dB1]); \
    gload_lds16(pB3,   &lds[bf][dB3]); \
    pA[0] += 32; pA[1] += 32; pB1 += 32; pB3 += 32; } while (0)
#define READS(cur) do { \
_Pragma("unroll") \
    for (int mi = 0; mi < 4; ++mi) \
      a[mi] = *(const s16x8*)&lds[cur][aBase + mi * 512]; \
_Pragma("unroll") \
    for (int n = 0; n < 2; ++n) { \
      b1[n] = *(const s16x8*)&lds[cur][b1Base + n * 512]; \
      b3[n] = *(const s16x8*)&lds[cur][b1Base + 2048 + n * 512]; \
    } } while (0)
#define MFMA16() do { \
    __builtin_amdgcn_s_setprio(1); \
_Pragma("unroll") \
    for (int mi = 0; mi < 4; ++mi) \
_Pragma("unroll") \
      for (int n = 0; n < 2; ++n) { \
        acc1[mi][n] = __builtin_amdgcn_mfma_f32_16x16x32_bf16(a[mi], b1[n], acc1[mi][n], 0, 0, 0); \
        acc3[mi][n] = __builtin_amdgcn_mfma_f32_16x16x32_bf16(a[mi], b3[n], acc3[mi][n], 0, 0, 0); \
      } \
    __builtin_amdgcn_s_setprio(0); } while (0)

  // main tile: stage t+3 into buf[(cur+3)&3]; wait tile t's 4 oldest loads
  // (12 newer stay in flight); BAR; read; BAR (certifies reads before any
  // wave's next-tile STG can overwrite buf[cur]); MFMA (reg-only).
#define TILE_MAIN(cur) do { \
    STG_ALL((cur + 3) & 3); \
    asm volatile("s_waitcnt vmcnt(12)" ::: "memory"); \
    __builtin_amdgcn_s_barrier(); \
    READS(cur); \
    __builtin_amdgcn_s_barrier(); \
    MFMA16(); } while (0)
#define TILE_TAIL(cur, N) do { \
    asm volatile("s_waitcnt vmcnt(" #N ")" ::: "memory"); \
    __builtin_amdgcn_s_barrier(); \
    READS(cur); \
    __builtin_amdgcn_s_barrier(); \
    MFMA16(); } while (0)

  // prologue: stage tiles 0,1,2 (12 loads in flight)
  STG_ALL(0);
  STG_ALL(1);
  STG_ALL(2);

  // tiles 0..60 main (stage t+3), tiles 61..63 tail
  for (int t = 0; t < KTILES - 4; t += 4) {
    TILE_MAIN(0);
    TILE_MAIN(1);
    TILE_MAIN(2);
    TILE_MAIN(3);
  }
  TILE_MAIN(0);        // t=60, stages buf 3 (tile 63)
  TILE_TAIL(1, 8);     // t=61
  TILE_TAIL(2, 4);     // t=62
  TILE_TAIL(3, 0);     // t=63

  // ---- epilogue
#pragma unroll
  for (int m = 0; m < 4; ++m)
#pragma unroll
    for (int n = 0; n < 2; ++n) {
      const int rloc = wr * 64 + m * 16 + kg * 4;
      if (EPI == 1) {
        const int col = colb * 64 + wc * 32 + n * 16 + lm;
#pragma unroll
        for (int rr = 0; rr < 4; ++rr) {
          int rowl = rloc + rr;
          if (rowl < vr) {
            float z = acc1[m][n][rr];
            float h = z / (1.f + __expf(-z)) * acc3[m][n][rr];
            out[(size_t)(row0 + rowl) * 2048 + col] = f2bf(h);
          }
        }
      } else {
        const int col = colb * 128 + wc * 32 + n * 16 + lm;
#pragma unroll
        for (int rr = 0; rr < 4; ++rr) {
          int rowl = rloc + rr;
          if (rowl < vr) {
            out[(size_t)(row0 + rowl) * 2048 + col] = f2bf(acc1[m][n][rr]);
            out[(size_t)(row0 + rowl) * 2048 + col + 64] = f2bf(acc3[m][n][rr]);
          }
        }
      }
    }
#undef STG_ALL
#undef READS
#undef MFMA16
#undef TILE_MAIN
#undef TILE_TAIL
}

__global__ __launch_bounds__(256, 2) void gemm1_kernel(
    const u16* __restrict__ A, const u16* __restrict__ B1m, const u16* __restrict__ B3m,
    const int* __restrict__ gather, const int* __restrict__ meta, u16* __restrict__ out) {
  gemm_body<1>(A, B1m, B3m, gather, meta, out);
}
__global__ __launch_bounds__(256, 2) void gemm2_kernel(
    const u16* __restrict__ A, const u16* __restrict__ B1m, const u16* __restrict__ B3m,
    const int* __restrict__ gather, const int* __restrict__ meta, u16* __restrict__ out) {
  gemm_body<0>(A, B1m, B3m, gather, meta, out);
}

// ---------------- combine ----------------
__global__ void combine_kernel(const u16* __restrict__ res, const int* __restrict__ posOf,
                               const float* __restrict__ ew, float* __restrict__ out) {
  int c = blockIdx.x * 256 + threadIdx.x;
  int t = c >> 8, dc = (c & 255) * 8;
  int p0 = posOf[2 * t], p1 = posOf[2 * t + 1];
  float wa = ew[2 * t], wb = ew[2 * t + 1];
  u16x8 u0 = *(const u16x8*)&res[(size_t)p0 * 2048 + dc];
  u16x8 u1 = *(const u16x8*)&res[(size_t)p1 * 2048 + dc];
  float4 o0, o1;
  o0.x = wa * bf2f(u0[0]) + wb * bf2f(u1[0]);
  o0.y = wa * bf2f(u0[1]) + wb * bf2f(u1[1]);
  o0.z = wa * bf2f(u0[2]) + wb * bf2f(u1[2]);
  o0.w = wa * bf2f(u0[3]) + wb * bf2f(u1[3]);
  o1.x = wa * bf2f(u0[4]) + wb * bf2f(u1[4]);
  o1.y = wa * bf2f(u0[5]) + wb * bf2f(u1[5]);
  o1.z = wa * bf2f(u0[6]) + wb * bf2f(u1[6]);
  o1.w = wa * bf2f(u0[7]) + wb * bf2f(u1[7]);
  *(float4*)&out[(size_t)t * 2048 + dc] = o0;
  *(float4*)&out[(size_t)t * 2048 + dc + 4] = o1;
}

extern "C" void kernel_launch(void* const* d_in, const int* in_sizes, int n_in,
                              void* d_out, int out_size, void* d_ws, size_t ws_size,
                              hipStream_t stream) {
  const float* x  = (const float*)d_in[0];
  const float* ew = (const float*)d_in[1];
  const int* eidx = (const int*)d_in[2];
  const int* bsz  = (const int*)d_in[3];
  const float* w1 = (const float*)d_in[4];
  const float* w2 = (const float*)d_in[5];
  const float* w3 = (const float*)d_in[6];
  float* out = (float*)d_out;
  char* ws = (char*)d_ws;

  if (ws_size < WS_NEED) {
    hipMemsetAsync(d_out, 0, (size_t)out_size * 4, stream);
    return;
  }

  u16* w1T = (u16*)(ws + W1T_OFF);
  u16* w3T = (u16*)(ws + W3T_OFF);
  u16* w2T = (u16*)(ws + W2T_OFF);
  u16* xbf = (u16*)(ws + XBF_OFF);
  u16* hs  = (u16*)(ws + HS_OFF);
  u16* res = (u16*)(ws + RES_OFF);   // overlays w1T/w3T (dead after gemm1)
  int* rowtok = (int*)(ws + ROWTOK_OFF);
  int* posOf  = (int*)(ws + POS_OFF);
  int* meta   = (int*)(ws + META_OFF);

  r1_kernel<<<1, 256, 0, stream>>>(bsz, meta, rowtok);
  r2_kernel<<<64, 256, 0, stream>>>(eidx, meta, rowtok, posOf);
  convert_x_kernel<<<8192, 256, 0, stream>>>(x, xbf);
  transpose_cvt_kernel<<<dim3(32, 32, 24), 256, 0, stream>>>(w1, w2, w3, w1T, w2T, w3T);
  gemm1_kernel<<<MAXTILES * 32, 256, 0, stream>>>(xbf, w1T, w3T, rowtok, meta, hs);
  gemm2_kernel<<<MAXTILES * 16, 256, 0, stream>>>(hs, w2T, w2T, nullptr, meta, res);
  combine_kernel<<<8192, 256, 0, stream>>>(res, posOf, ew, out);
}

// Round 12
// 691.009 us; speedup vs baseline: 1.3108x; 1.0659x over previous
//
#include <hip/hip_runtime.h>
#include <stdint.h>

typedef unsigned short u16;
typedef __attribute__((ext_vector_type(8))) short s16x8;
typedef __attribute__((ext_vector_type(8))) unsigned short u16x8;
typedef __attribute__((ext_vector_type(4))) float f32x4;

#define N_TOK 8192
#define DDIM 2048
#define HDIM 2048
#define NROWS 16384
#define PADROWS 16640
#define MAXTILES 72
#define KTILES 32

// ---- ws layout (bytes) ----
#define W1T_OFF    0ull
#define W3T_OFF    67108864ull
#define W2T_OFF    134217728ull
#define XBF_OFF    201326592ull
#define HS_OFF     234881024ull              // 16640 x 2048 bf16
#define ROWTOK_OFF 303038464ull
#define POS_OFF    303107072ull
#define META_OFF   303172608ull
#define RES_OFF    0ull                      // overlays w1T/w3T (dead after gemm1)
#define WS_NEED    303172736ull

__device__ __forceinline__ u16 f2bf(float f) {
  union { float f; unsigned u; } v; v.f = f;
  unsigned r = v.u + 0x7fffu + ((v.u >> 16) & 1u);
  return (u16)(r >> 16);
}
__device__ __forceinline__ float bf2f(u16 u) {
  union { unsigned u; float f; } v; v.u = ((unsigned)u) << 16; return v.f;
}
__device__ __forceinline__ void gload_lds16(const u16* g, u16* l) {
  __builtin_amdgcn_global_load_lds(
      (const __attribute__((address_space(1))) unsigned int*)g,
      (__attribute__((address_space(3))) unsigned int*)l, 16, 0, 0);
}

// ---------------- routing (256-row tiles) ----------------
__global__ void r1_kernel(const int* __restrict__ bsz, int* __restrict__ meta,
                          int* __restrict__ rowtok) {
  if (threadIdx.x == 0) {
    int off = 0, tbv = 0;
    meta[8] = 0; meta[17] = 0;
    for (int e = 0; e < 8; ++e) {
      meta[e] = 0;
      int c = bsz[e];
      off += c;  meta[9 + e] = off;
      tbv += (c + 255) >> 8; meta[18 + e] = tbv;
    }
  }
  for (int p = NROWS + (int)threadIdx.x; p < PADROWS; p += 256) rowtok[p] = 0;
}

__global__ void r2_kernel(const int* __restrict__ eidx, int* __restrict__ meta,
                          int* __restrict__ rowtok, int* __restrict__ posOf) {
  int i = blockIdx.x * 256 + threadIdx.x;
  int e = eidx[i];
  int p = atomicAdd(&meta[e], 1);
  int row = meta[8 + e] + p;
  rowtok[row] = i >> 1;
  posOf[i] = row;
}

// ---------------- converts ----------------
__global__ void convert_x_kernel(const float* __restrict__ x, u16* __restrict__ xbf) {
  long long c = blockIdx.x * 256 + threadIdx.x;
  const float4 v0 = *(const float4*)&x[c * 8];
  const float4 v1 = *(const float4*)&x[c * 8 + 4];
  u16x8 u;
  u[0] = f2bf(v0.x); u[1] = f2bf(v0.y); u[2] = f2bf(v0.z); u[3] = f2bf(v0.w);
  u[4] = f2bf(v1.x); u[5] = f2bf(v1.y); u[6] = f2bf(v1.z); u[7] = f2bf(v1.w);
  *(u16x8*)&xbf[c * 8] = u;
}

__global__ __launch_bounds__(256) void transpose_cvt_kernel(
    const float* __restrict__ w1, const float* __restrict__ w2, const float* __restrict__ w3,
    u16* __restrict__ w1T, u16* __restrict__ w2T, u16* __restrict__ w3T) {
  __shared__ float tile[64][65];
  int z = blockIdx.z;
  const float* src; u16* dst;
  if (z < 8)        { src = w1 + (size_t)z * 4194304;        dst = w1T + (size_t)z * 4194304; }
  else if (z < 16)  { src = w3 + (size_t)(z - 8) * 4194304;  dst = w3T + (size_t)(z - 8) * 4194304; }
  else              { src = w2 + (size_t)(z - 16) * 4194304; dst = w2T + (size_t)(z - 16) * 4194304; }
  int r0 = blockIdx.y * 64, c0 = blockIdx.x * 64;
  int tid = threadIdx.x;
  int lr = tid >> 4, lc4 = (tid & 15) * 4;
#pragma unroll
  for (int i = 0; i < 4; ++i) {
    const float4 v = *(const float4*)&src[(size_t)(r0 + lr + i * 16) * 2048 + c0 + lc4];
    tile[lr + i * 16][lc4 + 0] = v.x; tile[lr + i * 16][lc4 + 1] = v.y;
    tile[lr + i * 16][lc4 + 2] = v.z; tile[lr + i * 16][lc4 + 3] = v.w;
  }
  __syncthreads();
  int orb = tid >> 3, oc8 = (tid & 7) * 8;
#pragma unroll
  for (int i = 0; i < 2; ++i) {
    int orow = orb + i * 32;
    u16x8 u;
#pragma unroll
    for (int j = 0; j < 8; ++j) u[j] = f2bf(tile[oc8 + j][orow]);
    *(u16x8*)&dst[(size_t)(c0 + orow) * 2048 + r0 + oc8] = u;
  }
}

// ---------------- grouped dual-B GEMM, staggered 4-phase counted schedule ----------------
// Geometry/mapping/swizzles = R8 (proven). Hot loop = m201-style per-phase
// interleave {reads ∥ 2-load stage ∥ MFMA} with counted vmcnt.
// LEDGER (reads happen at phase start, BEFORE this phase's wait/barrier; a unit
// read at phase P must be certified by a wait+barrier at some phase <= P-1):
//   ph0 reads A0,A1,B1 (A-half0 via wr => units A0 AND A1!) ; ph1 reads B3 ;
//   ph2 reads A0,A1 (half1, already certified) ; ph3 no reads.
//   stage order: ph0 -> A0',B1' ; ph1 -> A1',B3'.
//   t ph0: in-flight B3(t)+4 = 6 -> vmcnt(4) certifies B3(t)   [read t ph1]
//   t ph3: in-flight 8          -> vmcnt(2) certifies A0',B1',A1' [read t+1 ph0]
//   B3' certified by t+1 ph0's vmcnt(4). Never drains in main loop.
// EPI=1: out[row][colb*128+c] = silu(A@B1) * (A@B3)
// EPI=0: out[row][colb*256+c] = A@B1 ; +128 = A@B3 (both = w2T sub-panels)
template<int EPI>
__device__ __forceinline__ void gemm_body(
    const u16* __restrict__ A, const u16* __restrict__ B1m, const u16* __restrict__ B3m,
    const int* __restrict__ gather, const int* __restrict__ meta, u16* __restrict__ out) {
  const int* offs = meta + 8;
  const int* tb = meta + 17;

  // XCD super-block locality mapping (8 tileIds x 4 colbs per super-block)
  const int NCOLB = EPI ? 16 : 8;
  const int CG = NCOLB / 4;
  const int nper = (MAXTILES * NCOLB) / 8;
  const int lin = (int)blockIdx.x;
  const int w = (lin & 7) * nper + (lin >> 3);
  const int sb = w >> 5, t5 = w & 31;
  const int tileId = (sb / CG) * 8 + (t5 >> 2);
  const int colb = (sb % CG) * 4 + (t5 & 3);

  if (tileId >= tb[8]) return;
  int e = 0;
#pragma unroll
  for (int qq = 1; qq < 8; ++qq) if (tileId >= tb[qq]) e = qq;
  const int row0 = offs[e] + (tileId - tb[e]) * 256;
  const int vr = offs[e + 1] - row0;

  const int bRowA = EPI ? colb * 128 : colb * 256;
  const int bRowB = EPI ? colb * 128 : colb * 256 + 128;

  __shared__ u16 lds[2][4][8192];  // [buf][A0,A1,B1,B3] = 128 KiB

  const int tid = threadIdx.x;
  const int wid = tid >> 6, lane = tid & 63;
  const int lm = lane & 15, kg = lane >> 4;
  const int wr = wid >> 2, wc = wid & 3;

  // stage pointers (2 gloads per unit per thread), chunk-permuted source
  const u16* pA0[2]; const u16* pA1[2]; const u16* pB1[2]; const u16* pB3[2];
#pragma unroll
  for (int l = 0; l < 2; ++l) {
    int S = (wid * 2 + l) * 64 + lane;
    int r = S >> 3;
    int c8 = ((S & 7) ^ (r & 7)) * 8;
    int ga0 = row0 + r, ga1 = row0 + 128 + r;
    int ta0 = gather ? gather[ga0] : ga0;
    int ta1 = gather ? gather[ga1] : ga1;
    pA0[l] = A + (size_t)ta0 * 2048 + c8;
    pA1[l] = A + (size_t)ta1 * 2048 + c8;
    pB1[l] = B1m + ((size_t)e * 2048 + bRowA + r) * 2048 + c8;
    pB3[l] = B3m + ((size_t)e * 2048 + bRowB + r) * 2048 + c8;
  }

  // frag-read offsets: elem = lm*64 + ((kk*4+kg)^(lm&7))*8
  int fA[2];
  fA[0] = lm * 64 + ((kg) ^ (lm & 7)) * 8;
  fA[1] = lm * 64 + ((4 + kg) ^ (lm & 7)) * 8;

  f32x4 acc1[8][2], acc3[8][2];
  f32x4 z4 = {0.f, 0.f, 0.f, 0.f};
#pragma unroll
  for (int m = 0; m < 8; ++m)
#pragma unroll
    for (int n = 0; n < 2; ++n) { acc1[m][n] = z4; acc3[m][n] = z4; }

  s16x8 a[4][2], b1r[2][2], b3r[2][2];

#define STG(b, u, P) do { \
    gload_lds16(P[0], &lds[b][u][(wid * 2 + 0) * 512]); \
    gload_lds16(P[1], &lds[b][u][(wid * 2 + 1) * 512]); \
    P[0] += 64; P[1] += 64; } while (0)
#define READ_A(cur, half) do { \
_Pragma("unroll") \
    for (int mi = 0; mi < 4; ++mi) \
_Pragma("unroll") \
      for (int kk = 0; kk < 2; ++kk) \
        a[mi][kk] = *(const s16x8*)&lds[cur][wr][((half) * 4 + mi) * 1024 + fA[kk]]; \
    } while (0)
#define READ_B1(cur) do { \
_Pragma("unroll") \
    for (int n = 0; n < 2; ++n) \
_Pragma("unroll") \
      for (int kk = 0; kk < 2; ++kk) \
        b1r[n][kk] = *(const s16x8*)&lds[cur][2][wc * 2048 + n * 1024 + fA[kk]]; \
    } while (0)
#define READ_B3(cur) do { \
_Pragma("unroll") \
    for (int n = 0; n < 2; ++n) \
_Pragma("unroll") \
      for (int kk = 0; kk < 2; ++kk) \
        b3r[n][kk] = *(const s16x8*)&lds[cur][3][wc * 2048 + n * 1024 + fA[kk]]; \
    } while (0)
#define MFMA16(ACC, half, B) do { \
    __builtin_amdgcn_s_setprio(1); \
_Pragma("unroll") \
    for (int mi = 0; mi < 4; ++mi) \
_Pragma("unroll") \
      for (int n = 0; n < 2; ++n) { \
        ACC[(half)*4+mi][n] = __builtin_amdgcn_mfma_f32_16x16x32_bf16(a[mi][0], B[n][0], ACC[(half)*4+mi][n], 0, 0, 0); \
        ACC[(half)*4+mi][n] = __builtin_amdgcn_mfma_f32_16x16x32_bf16(a[mi][1], B[n][1], ACC[(half)*4+mi][n], 0, 0, 0); \
      } \
    __builtin_amdgcn_s_setprio(0); } while (0)
#define ABAR() asm volatile("s_barrier" ::: "memory")
#define LGKM0_FENCE() do { asm volatile("s_waitcnt lgkmcnt(0)" ::: "memory"); \
    __builtin_amdgcn_sched_barrier(0); } while (0)

#define TILE_MAIN(cur) do { \
    /* ph0: reads certified by prev tile ph3 vmcnt(2)+ABAR */ \
    READ_A(cur, 0); READ_B1(cur); \
    STG(cur ^ 1, 0, pA0); STG(cur ^ 1, 2, pB1); \
    asm volatile("s_waitcnt vmcnt(4) lgkmcnt(8)" ::: "memory"); \
    ABAR(); LGKM0_FENCE(); \
    MFMA16(acc1, 0, b1r); \
    ABAR(); \
    /* ph1: B3(t) certified by ph0 vmcnt(4)+ABAR */ \
    READ_B3(cur); \
    STG(cur ^ 1, 1, pA1); STG(cur ^ 1, 3, pB3); \
    ABAR(); LGKM0_FENCE(); \
    MFMA16(acc3, 0, b3r); \
    ABAR(); \
    /* ph2: A half1 (units certified long ago) */ \
    READ_A(cur, 1); \
    ABAR(); LGKM0_FENCE(); \
    MFMA16(acc1, 1, b1r); \
    ABAR(); \
    /* ph3: certify next tile's A0',B1',A1' */ \
    asm volatile("s_waitcnt vmcnt(2)" ::: "memory"); \
    ABAR(); \
    MFMA16(acc3, 1, b3r); \
    ABAR(); } while (0)

#define TILE_LAST(cur) do { \
    READ_A(cur, 0); READ_B1(cur); \
    asm volatile("s_waitcnt vmcnt(0) lgkmcnt(8)" ::: "memory"); \
    ABAR(); LGKM0_FENCE(); \
    MFMA16(acc1, 0, b1r); \
    ABAR(); \
    READ_B3(cur); \
    ABAR(); LGKM0_FENCE(); \
    MFMA16(acc3, 0, b3r); \
    ABAR(); \
    READ_A(cur, 1); \
    ABAR(); LGKM0_FENCE(); \
    MFMA16(acc1, 1, b1r); \
    ABAR(); \
    MFMA16(acc3, 1, b3r); } while (0)

  // prologue: issue tile 0 in ledger order A0,B1,A1,B3; certify A0,B1,A1
  STG(0, 0, pA0);
  STG(0, 2, pB1);
  STG(0, 1, pA1);
  STG(0, 3, pB3);
  asm volatile("s_waitcnt vmcnt(2)" ::: "memory");
  ABAR();

  for (int t = 0; t < KTILES - 2; t += 2) {
    TILE_MAIN(0);
    TILE_MAIN(1);
  }
  TILE_MAIN(0);
  TILE_LAST(1);

  // ---- epilogue
#pragma unroll
  for (int m = 0; m < 8; ++m)
#pragma unroll
    for (int n = 0; n < 2; ++n) {
      const int rloc = wr * 128 + m * 16 + kg * 4;
      if (EPI == 1) {
        const int col = colb * 128 + wc * 32 + n * 16 + lm;
#pragma unroll
        for (int rr = 0; rr < 4; ++rr) {
          int rowl = rloc + rr;
          if (rowl < vr) {
            float z = acc1[m][n][rr];
            float h = z / (1.f + __expf(-z)) * acc3[m][n][rr];
            out[(size_t)(row0 + rowl) * 2048 + col] = f2bf(h);
          }
        }
      } else {
        const int col = colb * 256 + wc * 32 + n * 16 + lm;
#pragma unroll
        for (int rr = 0; rr < 4; ++rr) {
          int rowl = rloc + rr;
          if (rowl < vr) {
            out[(size_t)(row0 + rowl) * 2048 + col] = f2bf(acc1[m][n][rr]);
            out[(size_t)(row0 + rowl) * 2048 + col + 128] = f2bf(acc3[m][n][rr]);
          }
        }
      }
    }
#undef STG
#undef READ_A
#undef READ_B1
#undef READ_B3
#undef MFMA16
#undef ABAR
#undef LGKM0_FENCE
#undef TILE_MAIN
#undef TILE_LAST
}

__global__ __launch_bounds__(512, 2) void gemm1_kernel(
    const u16* __restrict__ A, const u16* __restrict__ B1m, const u16* __restrict__ B3m,
    const int* __restrict__ gather, const int* __restrict__ meta, u16* __restrict__ out) {
  gemm_body<1>(A, B1m, B3m, gather, meta, out);
}
__global__ __launch_bounds__(512, 2) void gemm2_kernel(
    const u16* __restrict__ A, const u16* __restrict__ B1m, const u16* __restrict__ B3m,
    const int* __restrict__ gather, const int* __restrict__ meta, u16* __restrict__ out) {
  gemm_body<0>(A, B1m, B3m, gather, meta, out);
}

// ---------------- combine ----------------
__global__ void combine_kernel(const u16* __restrict__ res, const int* __restrict__ posOf,
                               const float* __restrict__ ew, float* __restrict__ out) {
  int c = blockIdx.x * 256 + threadIdx.x;
  int t = c >> 8, dc = (c & 255) * 8;
  int p0 = posOf[2 * t], p1 = posOf[2 * t + 1];
  float wa = ew[2 * t], wb = ew[2 * t + 1];
  u16x8 u0 = *(const u16x8*)&res[(size_t)p0 * 2048 + dc];
  u16x8 u1 = *(const u16x8*)&res[(size_t)p1 * 2048 + dc];
  float4 o0, o1;
  o0.x = wa * bf2f(u0[0]) + wb * bf2f(u1[0]);
  o0.y = wa * bf2f(u0[1]) + wb * bf2f(u1[1]);
  o0.z = wa * bf2f(u0[2]) + wb * bf2f(u1[2]);
  o0.w = wa * bf2f(u0[3]) + wb * bf2f(u1[3]);
  o1.x = wa * bf2f(u0[4]) + wb * bf2f(u1[4]);
  o1.y = wa * bf2f(u0[5]) + wb * bf2f(u1[5]);
  o1.z = wa * bf2f(u0[6]) + wb * bf2f(u1[6]);
  o1.w = wa * bf2f(u0[7]) + wb * bf2f(u1[7]);
  *(float4*)&out[(size_t)t * 2048 + dc] = o0;
  *(float4*)&out[(size_t)t * 2048 + dc + 4] = o1;
}

extern "C" void kernel_launch(void* const* d_in, const int* in_sizes, int n_in,
                              void* d_out, int out_size, void* d_ws, size_t ws_size,
                              hipStream_t stream) {
  const float* x  = (const float*)d_in[0];
  const float* ew = (const float*)d_in[1];
  const int* eidx = (const int*)d_in[2];
  const int* bsz  = (const int*)d_in[3];
  const float* w1 = (const float*)d_in[4];
  const float* w2 = (const float*)d_in[5];
  const float* w3 = (const float*)d_in[6];
  float* out = (float*)d_out;
  char* ws = (char*)d_ws;

  if (ws_size < WS_NEED) {
    hipMemsetAsync(d_out, 0, (size_t)out_size * 4, stream);
    return;
  }

  u16* w1T = (u16*)(ws + W1T_OFF);
  u16* w3T = (u16*)(ws + W3T_OFF);
  u16* w2T = (u16*)(ws + W2T_OFF);
  u16* xbf = (u16*)(ws + XBF_OFF);
  u16* hs  = (u16*)(ws + HS_OFF);
  u16* res = (u16*)(ws + RES_OFF);   // overlays w1T/w3T (dead after gemm1)
  int* rowtok = (int*)(ws + ROWTOK_OFF);
  int* posOf  = (int*)(ws + POS_OFF);
  int* meta   = (int*)(ws + META_OFF);

  r1_kernel<<<1, 256, 0, stream>>>(bsz, meta, rowtok);
  r2_kernel<<<64, 256, 0, stream>>>(eidx, meta, rowtok, posOf);
  convert_x_kernel<<<8192, 256, 0, stream>>>(x, xbf);
  transpose_cvt_kernel<<<dim3(32, 32, 24), 256, 0, stream>>>(w1, w2, w3, w1T, w2T, w3T);
  gemm1_kernel<<<MAXTILES * 16, 512, 0, stream>>>(xbf, w1T, w3T, rowtok, meta, hs);
  gemm2_kernel<<<MAXTILES * 8, 512, 0, stream>>>(hs, w2T, w2T, nullptr, meta, res);
  combine_kernel<<<8192, 256, 0, stream>>>(res, posOf, ew, out);
}